// Round 1
// baseline (166.190 us; speedup 1.0000x reference)
//
#include <hip/hip_runtime.h>
#include <hip/hip_bf16.h>

// B=4, T=2048, SD=64, NE=4096, H=8, HS=8, FH=256
// All reshapes in the reference are flat reinterpretations -> one flat buffer
// per intermediate works for every "view".

#define BT_STRIDE 131072   // T*SD = per-batch elements of h
#define EPSF 1e-5f

// ---------------- K1: Feebler  h[b,i,t'] = sum_j x[b,i,j,t'] * fw[i,j,t'] ----
// write to flat h buffer at b*131072 + i*2048 + t'
__global__ void k1_feebler(const float* __restrict__ x, const float* __restrict__ fw,
                           float* __restrict__ h) {
    int bi = blockIdx.x;            // 0..255  (b*64+i)
    int b = bi >> 6, i = bi & 63;
    int t4 = blockIdx.y * 256 + threadIdx.x;   // float4 index 0..511
    const float4* x4 = (const float4*)x;
    const float4* f4 = (const float4*)fw;
    float4 acc = make_float4(0.f, 0.f, 0.f, 0.f);
    size_t xb = (size_t)b * 2097152 + (size_t)i * 32768 + t4;
    size_t fb = (size_t)i * 32768 + t4;
    for (int j = 0; j < 64; ++j) {
        float4 xv = x4[xb + (size_t)j * 512];
        float4 fv = f4[fb + (size_t)j * 512];
        acc.x += xv.x * fv.x; acc.y += xv.y * fv.y;
        acc.z += xv.z * fv.z; acc.w += xv.w * fv.w;
    }
    ((float4*)h)[(size_t)b * 32768 + (size_t)i * 512 + t4] = acc;
}

// ---------------- K2a: LayerNorm1 row-wise + column sums of y ----------------
__global__ void k2a_ln1(const float* __restrict__ h, const float* __restrict__ g,
                        const float* __restrict__ bia, float* __restrict__ y,
                        float* __restrict__ ysum) {
    int blk = blockIdx.x;           // 64 blocks: b*16 + chunk
    int b = blk >> 4, t0 = (blk & 15) * 128;
    int lane = threadIdx.x & 63, w = threadIdx.x >> 6;
    float gv = g[lane], bv = bia[lane];
    float colsum = 0.f;
    for (int k = 0; k < 32; ++k) {
        int t = t0 + w + 4 * k;
        size_t idx = (size_t)b * BT_STRIDE + (size_t)t * 64 + lane;
        float v = h[idx];
        float s1 = v, s2 = v * v;
        for (int off = 32; off; off >>= 1) {
            s1 += __shfl_xor(s1, off);
            s2 += __shfl_xor(s2, off);
        }
        float m = s1 * (1.f / 64.f);
        float var = s2 * (1.f / 64.f) - m * m;
        float rs = rsqrtf(var + EPSF);
        float yv = (v - m) * rs * gv + bv;
        y[idx] = yv;
        colsum += yv;
    }
    atomicAdd(&ysum[b * 64 + lane], colsum);
}

// ---------------- K2b: ck/cv = ysum @ Wk / Wv  (tiny) ------------------------
__global__ void k2b_ckcv(const float* __restrict__ ysum, const float* __restrict__ wk,
                         const float* __restrict__ wv, float* __restrict__ ck,
                         float* __restrict__ cv) {
    int tid = threadIdx.x;          // 256 = B*64
    int b = tid >> 6, c = tid & 63, hh = c >> 3, d = c & 7;
    float a = 0.f, e = 0.f;
    for (int s = 0; s < 64; ++s) {
        float ys = ysum[b * 64 + s];
        a += ys * wk[hh * 512 + s * 8 + d];
        e += ys * wv[hh * 512 + s * 8 + d];
    }
    ck[tid] = a;
    cv[tid] = e;
}

// ---------------- K2c: qc = (y@Wq)*ck, global column max ---------------------
__global__ void k2c_qmax(const float* __restrict__ y, const float* __restrict__ wq,
                         const float* __restrict__ ck, float* __restrict__ qc,
                         unsigned* __restrict__ umax) {
    __shared__ float yL[64][64];
    __shared__ float wqL[64][64];
    __shared__ float pmax[4][64];
    int b = blockIdx.x, t0 = blockIdx.y * 64;
    int tid = threadIdx.x;
    for (int kk = 0; kk < 16; ++kk) {
        int idx = kk * 256 + tid;
        int r = idx >> 6, cc = idx & 63;
        yL[r][cc] = y[(size_t)b * BT_STRIDE + (size_t)(t0 + r) * 64 + cc];
        wqL[r][cc] = wq[(cc >> 3) * 512 + r * 8 + (cc & 7)];
    }
    __syncthreads();
    int c = tid & 63, tq = tid >> 6;
    float ckc = ck[b * 64 + c];
    float lmax = -3.4e38f;
    for (int k = 0; k < 16; ++k) {
        int t = k * 4 + tq;
        float a = 0.f;
        for (int s = 0; s < 64; ++s) a += yL[t][s] * wqL[s][c];
        float v = a * ckc;
        qc[(size_t)b * BT_STRIDE + (size_t)(t0 + t) * 64 + c] = v;
        lmax = fmaxf(lmax, v);
    }
    pmax[tq][c] = lmax;
    __syncthreads();
    if (tid < 64) {
        float m = fmaxf(fmaxf(pmax[0][tid], pmax[1][tid]),
                        fmaxf(pmax[2][tid], pmax[3][tid]));
        unsigned u = __float_as_uint(m);
        u = (u & 0x80000000u) ? ~u : (u | 0x80000000u);   // monotonic key
        atomicMax(&umax[b * 64 + tid], u);
    }
}

// ---------------- K2d: e = exp(qc - m) in place, column sums -----------------
__global__ void k2d_expsum(float* __restrict__ qc, const unsigned* __restrict__ umax,
                           float* __restrict__ denom) {
    __shared__ float psum[4][64];
    int b = blockIdx.x, t0 = blockIdx.y * 64;
    int tid = threadIdx.x, c = tid & 63, tq = tid >> 6;
    unsigned u = umax[b * 64 + c];
    unsigned bits = (u & 0x80000000u) ? (u ^ 0x80000000u) : ~u;
    float m = __uint_as_float(bits);
    float ls = 0.f;
    for (int k = 0; k < 16; ++k) {
        int t = k * 4 + tq;
        size_t idx = (size_t)b * BT_STRIDE + (size_t)(t0 + t) * 64 + c;
        float e = __expf(qc[idx] - m);
        qc[idx] = e;
        ls += e;
    }
    psum[tq][c] = ls;
    __syncthreads();
    if (tid < 64)
        atomicAdd(&denom[b * 64 + tid],
                  psum[0][tid] + psum[1][tid] + psum[2][tid] + psum[3][tid]);
}

// ------- K2e: sa = (e*cv/denom)@proj_w + proj_b; h+=sa; LN2; FFN; h+=f -------
__global__ void k2e_mid(const float* __restrict__ h, const float* __restrict__ qc,
                        const float* __restrict__ cv, const float* __restrict__ denom,
                        const float* __restrict__ projw, const float* __restrict__ projb,
                        const float* __restrict__ g2, const float* __restrict__ b2l,
                        const float* __restrict__ w1, const float* __restrict__ b1,
                        const float* __restrict__ w2, const float* __restrict__ b2f,
                        float* __restrict__ hf) {
    __shared__ float pL[4][8][64];
    __shared__ float y2L[4][8][64];
    __shared__ float hidL[4][8][256];
    int b = blockIdx.x, t0 = blockIdx.y * 32;
    int tid = threadIdx.x, l = tid & 63, w = tid >> 6;
    float scl = cv[b * 64 + l] / denom[b * 64 + l];
    size_t base = (size_t)b * BT_STRIDE + (size_t)(t0 + w * 8) * 64 + l;
    #pragma unroll
    for (int rr = 0; rr < 8; ++rr) pL[w][rr][l] = qc[base + rr * 64] * scl;
    __syncthreads();

    // proj: a[rr] = sum_c p[c]*projw[c][l]
    float a[8], hmid[8];
    float pb = projb[l];
    #pragma unroll
    for (int rr = 0; rr < 8; ++rr) a[rr] = 0.f;
    for (int c = 0; c < 64; ++c) {
        float pw = projw[c * 64 + l];
        #pragma unroll
        for (int rr = 0; rr < 8; ++rr) a[rr] += pL[w][rr][c] * pw;
    }
    float gv = g2[l], bv = b2l[l];
    #pragma unroll
    for (int rr = 0; rr < 8; ++rr) {
        hmid[rr] = h[base + rr * 64] + a[rr] + pb;
        float v = hmid[rr];
        float s1 = v, s2 = v * v;
        for (int off = 32; off; off >>= 1) {
            s1 += __shfl_xor(s1, off);
            s2 += __shfl_xor(s2, off);
        }
        float mm = s1 * (1.f / 64.f);
        float var = s2 * (1.f / 64.f) - mm * mm;
        float rs = rsqrtf(var + EPSF);
        y2L[w][rr][l] = (v - mm) * rs * gv + bv;
    }
    __syncthreads();

    // FFN layer 1: hid[j] = relu(b1[j] + sum_s y2[s]*w1[s][j]),  j = u*64+l
    float h1[4][8];
    #pragma unroll
    for (int u = 0; u < 4; ++u) {
        float bb = b1[u * 64 + l];
        #pragma unroll
        for (int rr = 0; rr < 8; ++rr) h1[u][rr] = bb;
    }
    for (int s = 0; s < 64; ++s) {
        float yv[8];
        #pragma unroll
        for (int rr = 0; rr < 8; ++rr) yv[rr] = y2L[w][rr][s];
        #pragma unroll
        for (int u = 0; u < 4; ++u) {
            float w1v = w1[s * 256 + u * 64 + l];
            #pragma unroll
            for (int rr = 0; rr < 8; ++rr) h1[u][rr] += yv[rr] * w1v;
        }
    }
    #pragma unroll
    for (int u = 0; u < 4; ++u)
        #pragma unroll
        for (int rr = 0; rr < 8; ++rr)
            hidL[w][rr][u * 64 + l] = fmaxf(h1[u][rr], 0.f);
    __syncthreads();

    // FFN layer 2 + residual
    float a2[8];
    float b2v = b2f[l];
    #pragma unroll
    for (int rr = 0; rr < 8; ++rr) a2[rr] = b2v;
    for (int j = 0; j < 256; ++j) {
        float w2v = w2[j * 64 + l];
        #pragma unroll
        for (int rr = 0; rr < 8; ++rr) a2[rr] += hidL[w][rr][j] * w2v;
    }
    #pragma unroll
    for (int rr = 0; rr < 8; ++rr) hf[base + rr * 64] = hmid[rr] + a2[rr];
}

// ---------------- K3: Booster out[b,i,j,t'] = bw[i,j,t'] * hf[b, j*T+t'] -----
__global__ void k3_boost(const float* __restrict__ hf, const float* __restrict__ bw,
                         float* __restrict__ out) {
    int i = blockIdx.x;                     // 0..63
    int jc = blockIdx.y;                    // 0..3
    int t4 = blockIdx.z * 256 + threadIdx.x;  // 0..511
    const float4* bw4 = (const float4*)bw;
    const float4* hf4 = (const float4*)hf;
    float4* o4 = (float4*)out;
    for (int jj = 0; jj < 16; ++jj) {
        int j = jc * 16 + jj;
        float4 wv = bw4[(size_t)(i * 64 + j) * 512 + t4];
        #pragma unroll
        for (int b = 0; b < 4; ++b) {
            float4 hv = hf4[(size_t)b * 32768 + (size_t)j * 512 + t4];
            float4 ov;
            ov.x = wv.x * hv.x; ov.y = wv.y * hv.y;
            ov.z = wv.z * hv.z; ov.w = wv.w * hv.w;
            o4[(((size_t)(b * 64 + i)) * 64 + j) * 512 + t4] = ov;
        }
    }
}

extern "C" void kernel_launch(void* const* d_in, const int* in_sizes, int n_in,
                              void* d_out, int out_size, void* d_ws, size_t ws_size,
                              hipStream_t stream) {
    const float* x     = (const float*)d_in[0];
    const float* fw    = (const float*)d_in[1];
    const float* bw    = (const float*)d_in[2];
    const float* wq    = (const float*)d_in[3];
    const float* wk    = (const float*)d_in[4];
    const float* wv    = (const float*)d_in[5];
    const float* projw = (const float*)d_in[6];
    const float* projb = (const float*)d_in[7];
    const float* g1    = (const float*)d_in[8];
    const float* b1l   = (const float*)d_in[9];
    const float* g2    = (const float*)d_in[10];
    const float* b2l   = (const float*)d_in[11];
    const float* w1    = (const float*)d_in[12];
    const float* b1    = (const float*)d_in[13];
    const float* w2    = (const float*)d_in[14];
    const float* b2    = (const float*)d_in[15];
    float* out = (float*)d_out;

    float* wsf   = (float*)d_ws;
    float* h     = wsf;                     // 524288
    float* y     = wsf + 524288;            // 524288
    float* qc    = wsf + 1048576;           // 524288 (qc, then e in place)
    float* hf    = wsf + 1572864;           // 524288
    float* ysum  = wsf + 2097152;           // 256
    float* ck    = wsf + 2097408;           // 256
    float* cvb   = wsf + 2097664;           // 256
    unsigned* um = (unsigned*)(wsf + 2097920); // 256
    float* denom = wsf + 2098176;           // 256

    // zero ysum/ck/cv/umax/denom (umax key 0 == below -inf)
    hipMemsetAsync(ysum, 0, 1280 * sizeof(float), stream);

    k1_feebler<<<dim3(256, 2), 256, 0, stream>>>(x, fw, h);
    k2a_ln1<<<64, 256, 0, stream>>>(h, g1, b1l, y, ysum);
    k2b_ckcv<<<1, 256, 0, stream>>>(ysum, wk, wv, ck, cvb);
    k2c_qmax<<<dim3(4, 32), 256, 0, stream>>>(y, wq, ck, qc, um);
    k2d_expsum<<<dim3(4, 32), 256, 0, stream>>>(qc, um, denom);
    k2e_mid<<<dim3(4, 64), 256, 0, stream>>>(h, qc, cvb, denom, projw, projb,
                                             g2, b2l, w1, b1, w2, b2, hf);
    k3_boost<<<dim3(64, 4, 2), 256, 0, stream>>>(hf, bw, out);
}